// Round 9
// baseline (98.343 us; speedup 1.0000x reference)
//
#include <hip/hip_runtime.h>
#include <math.h>

#define BB 64
#define NN 2000
#define HH 128
#define NHEAD 8
#define SPB 16           // splits per batch for kB/kD/kE
#define RPB 125          // rows per block (SPB*RPB == NN)

// ---------------- k1qk: qk[b][h][:] , one block per (b,h) ----------------
__global__ __launch_bounds__(64) void k1qk(
    const float* __restrict__ pe, const float* __restrict__ cls,
    const float* __restrict__ Wqg, const float* __restrict__ Wqf,
    const float* __restrict__ Wql, const float* __restrict__ Wk,
    const int* __restrict__ lp, float* __restrict__ qk_out) {
  const int blk = blockIdx.x, b = blk >> 3, h = blk & 7;
  const int t = threadIdx.x;
  __shared__ float4 sc4[32], sl4[32];
  __shared__ float qs[16];
  const int last = lp[b];
  if (t < 32) sc4[t] = ((const float4*)(cls + b*HH))[t];
  else        sl4[t-32] = ((const float4*)(pe + ((long)b*NN + last)*HH))[t-32];
  __syncthreads();
  {
    const int dot = t >> 2, part = t & 3;
    const float4* wg = (const float4*)(Wqg + (h*16+dot)*HH) + part*8;
    const float4* wf = (const float4*)(Wqf + (h*16+dot)*HH) + part*8;
    const float4* wl = (const float4*)(Wql + (h*16+dot)*HH) + part*8;
    float a = 0.f;
    #pragma unroll
    for (int k = 0; k < 8; k++) {
      float4 g = wg[k], f = wf[k], l = wl[k];
      float4 c = sc4[part*8+k], s = sl4[part*8+k];
      a += g.x*c.x + g.y*c.y + g.z*c.z + g.w*c.w;
      a += (f.x+l.x)*s.x + (f.y+l.y)*s.y + (f.z+l.z)*s.z + (f.w+l.w)*s.w;
    }
    a += __shfl_xor(a, 1);
    a += __shfl_xor(a, 2);
    if (part == 0) qs[dot] = a;
  }
  __syncthreads();
  float v0 = 0.f, v1 = 0.f;
  #pragma unroll
  for (int d2 = 0; d2 < 16; d2++) {
    const float* wkr = Wk + (h*16+d2)*HH;
    float q = qs[d2];
    v0 += q * wkr[t];
    v1 += q * wkr[t+64];
  }
  qk_out[(b*NHEAD+h)*HH + t]      = v0 * 0.25f;   // fold 1/sqrt(head_dim)
  qk_out[(b*NHEAD+h)*HH + t + 64] = v1 * 0.25f;
}

// ---------------- kB: scores (2 threads/row) + weighted sums ----------------
__global__ __launch_bounds__(256) void kB(
    const float* __restrict__ pe, const float* __restrict__ qk,
    const int* __restrict__ lp, float* __restrict__ Wpart,
    float* __restrict__ lpart) {
  const int b = blockIdx.y, sp = blockIdx.x, tid = threadIdx.x;
  __shared__ float  pl[RPB][NHEAD];
  __shared__ float4 wred[NHEAD][4][32];
  __shared__ float  lred[4][NHEAD];
  const int last = lp[b];
  const int n0 = sp * RPB;

  // phase A: 2 threads per row, each owns a 64-float half-row
  {
    const int row = tid >> 1, half = tid & 1;
    if (row < RPB) {
      const int n = n0 + row;
      const float4* prow = (const float4*)(pe + ((long)b*NN + n)*HH) + half*16;
      const float4* qk4  = (const float4*)(qk + (long)b*NHEAD*HH) + half*16; // uniform -> s_load
      float4 r[16];
      #pragma unroll
      for (int j = 0; j < 16; j++) r[j] = prow[j];     // 16 loads in flight
      float d[NHEAD];
      #pragma unroll
      for (int h = 0; h < NHEAD; h++) d[h] = 0.f;
      #pragma unroll
      for (int j = 0; j < 16; j++) {
        const float4 v = r[j];
        #pragma unroll
        for (int h = 0; h < NHEAD; h++) {
          const float4 q = qk4[h*32 + j];
          d[h] += v.x*q.x + v.y*q.y + v.z*q.z + v.w*q.w;
        }
      }
      #pragma unroll
      for (int h = 0; h < NHEAD; h++) d[h] += __shfl_xor(d[h], 1);  // combine halves
      if (half == 0) {
        const bool live = (n != last);
        #pragma unroll
        for (int h = 0; h < NHEAD; h++) pl[row][h] = live ? __expf(d[h]) : 0.f;
      }
    }
  }
  __syncthreads();

  // phase B: W[h][:] += p[n][h] * pe[n][:], coalesced re-read (L2-hot)
  const int w = tid >> 6, lane = tid & 63;
  const int st = w*2 + (lane >> 5);     // row stream 0..7
  const int j4 = lane & 31;
  const float4* peg = (const float4*)(pe + ((long)b*NN + n0)*HH);
  float4 wa[NHEAD];
  float  la[NHEAD];
  #pragma unroll
  for (int h = 0; h < NHEAD; h++) { wa[h] = make_float4(0.f,0.f,0.f,0.f); la[h] = 0.f; }
  #pragma unroll 4
  for (int i = 0; i < 16; i++) {
    const int nl = st + (i << 3);
    if (nl < RPB) {
      float4 v  = peg[nl*32 + j4];
      float4 pa = *(const float4*)&pl[nl][0];
      float4 pb = *(const float4*)&pl[nl][4];
      wa[0].x += pa.x*v.x; wa[0].y += pa.x*v.y; wa[0].z += pa.x*v.z; wa[0].w += pa.x*v.w; la[0] += pa.x;
      wa[1].x += pa.y*v.x; wa[1].y += pa.y*v.y; wa[1].z += pa.y*v.z; wa[1].w += pa.y*v.w; la[1] += pa.y;
      wa[2].x += pa.z*v.x; wa[2].y += pa.z*v.y; wa[2].z += pa.z*v.z; wa[2].w += pa.z*v.w; la[2] += pa.z;
      wa[3].x += pa.w*v.x; wa[3].y += pa.w*v.y; wa[3].z += pa.w*v.z; wa[3].w += pa.w*v.w; la[3] += pa.w;
      wa[4].x += pb.x*v.x; wa[4].y += pb.x*v.y; wa[4].z += pb.x*v.z; wa[4].w += pb.x*v.w; la[4] += pb.x;
      wa[5].x += pb.y*v.x; wa[5].y += pb.y*v.y; wa[5].z += pb.y*v.z; wa[5].w += pb.y*v.w; la[5] += pb.y;
      wa[6].x += pb.z*v.x; wa[6].y += pb.z*v.y; wa[6].z += pb.z*v.z; wa[6].w += pb.z*v.w; la[6] += pb.z;
      wa[7].x += pb.w*v.x; wa[7].y += pb.w*v.y; wa[7].z += pb.w*v.z; wa[7].w += pb.w*v.w; la[7] += pb.w;
    }
  }
  #pragma unroll
  for (int h = 0; h < NHEAD; h++) {     // merge the two half-wave streams
    wa[h].x += __shfl_xor(wa[h].x, 32);
    wa[h].y += __shfl_xor(wa[h].y, 32);
    wa[h].z += __shfl_xor(wa[h].z, 32);
    wa[h].w += __shfl_xor(wa[h].w, 32);
    la[h]   += __shfl_xor(la[h], 32);
  }
  if (lane < 32) {
    #pragma unroll
    for (int h = 0; h < NHEAD; h++) wred[h][w][lane] = wa[h];
  }
  if (lane == 0) {
    #pragma unroll
    for (int h = 0; h < NHEAD; h++) lred[w][h] = la[h];
  }
  __syncthreads();
  {
    const int h2 = tid >> 5, c = tid & 31;
    float4 s0 = wred[h2][0][c], s1 = wred[h2][1][c];
    float4 s2 = wred[h2][2][c], s3 = wred[h2][3][c];
    float4 s;
    s.x = s0.x + s1.x + s2.x + s3.x;
    s.y = s0.y + s1.y + s2.y + s3.y;
    s.z = s0.z + s1.z + s2.z + s3.z;
    s.w = s0.w + s1.w + s2.w + s3.w;
    ((float4*)(Wpart + ((long)(b*SPB + sp)*NHEAD + h2)*HH))[c] = s;
  }
  if (tid < NHEAD)
    lpart[(b*SPB + sp)*NHEAD + tid] =
        lred[0][tid] + lred[1][tid] + lred[2][tid] + lred[3][tid];
}

// ---------------- kC: combine splits + matvec chain -> lq ----------------
__global__ __launch_bounds__(256) void kC(
    const float* __restrict__ lpart, const float* __restrict__ Wpart,
    const float* __restrict__ Wv, const float* __restrict__ Wc,
    const float* __restrict__ bc, const float* __restrict__ lWk,
    float* __restrict__ lq) {
  const int b = blockIdx.x, tid = threadIdx.x;
  __shared__ float Wns[NHEAD*HH];
  __shared__ float lsm[NHEAD];
  __shared__ float tmp[2][HH];
  __shared__ float outf[HH], fq[HH];
  for (int e = tid; e < NHEAD*HH; e += 256) {
    float a = 0.f;
    #pragma unroll 4
    for (int s = 0; s < SPB; s++) a += Wpart[((long)(b*SPB+s)*NHEAD)*HH + e];
    Wns[e] = a;
  }
  if (tid < NHEAD) {
    float l = 0.f;
    #pragma unroll
    for (int s = 0; s < SPB; s++) l += lpart[(b*SPB+s)*NHEAD + tid];
    lsm[tid] = l;
  }
  __syncthreads();
  const int t = tid & 127, half = tid >> 7;
  {
    const int h = t >> 4;
    const float4* wv = (const float4*)(Wv + t*HH);
    const float4* wn = (const float4*)(Wns + h*HH);
    float a = 0.f;
    #pragma unroll 4
    for (int j = half*16; j < half*16 + 16; j++) {
      float4 v = wv[j], nn = wn[j];
      a += v.x*nn.x + v.y*nn.y + v.z*nn.z + v.w*nn.w;
    }
    tmp[half][t] = a;
    __syncthreads();
    if (half == 0) outf[t] = (tmp[0][t] + tmp[1][t]) / lsm[t>>4];
    __syncthreads();
  }
  {
    const float4* wc = (const float4*)(Wc + t*HH);
    const float4* of = (const float4*)outf;
    float a = 0.f;
    #pragma unroll 4
    for (int k = half*16; k < half*16 + 16; k++) {
      float4 v = wc[k], nn = of[k];
      a += v.x*nn.x + v.y*nn.y + v.z*nn.z + v.w*nn.w;
    }
    tmp[half][t] = a;
    __syncthreads();
    if (half == 0) fq[t] = tmp[0][t] + tmp[1][t] + bc[t];
    __syncthreads();
  }
  {
    float a = 0.f;
    #pragma unroll 4
    for (int i = half*64; i < half*64 + 64; i++)
      a += fq[i] * lWk[i*HH + t];
    tmp[half][t] = a;
    __syncthreads();
    if (half == 0)
      lq[b*HH + t] = (tmp[0][t] + tmp[1][t]) * 0.08838834764831845f;  // 1/sqrt(128)
  }
}

// ---------------- kD: logits (2 threads/row) -> unnormalized e + psum ----------------
__global__ __launch_bounds__(256) void kD(
    const float* __restrict__ pe, const float* __restrict__ lq,
    const int* __restrict__ lp, float* __restrict__ out,
    float* __restrict__ psum) {
  const int b = blockIdx.y, sp = blockIdx.x, tid = threadIdx.x;
  __shared__ float red[4];
  const int last = lp[b];
  const int row = tid >> 1, half = tid & 1;
  const int n = sp*RPB + row;
  float e = 0.f;
  if (row < RPB) {
    const float4* prow = (const float4*)(pe + ((long)b*NN + n)*HH) + half*16;
    const float4* lq4  = (const float4*)(lq + (long)b*HH) + half*16;  // uniform -> s_load
    float4 r[16];
    #pragma unroll
    for (int j = 0; j < 16; j++) r[j] = prow[j];
    float a0 = 0.f, a1 = 0.f, a2 = 0.f, a3 = 0.f;
    #pragma unroll
    for (int j = 0; j < 16; j += 4) {
      float4 q0 = lq4[j], q1 = lq4[j+1], q2 = lq4[j+2], q3 = lq4[j+3];
      a0 += r[j].x*q0.x + r[j].y*q0.y + r[j].z*q0.z + r[j].w*q0.w;
      a1 += r[j+1].x*q1.x + r[j+1].y*q1.y + r[j+1].z*q1.z + r[j+1].w*q1.w;
      a2 += r[j+2].x*q2.x + r[j+2].y*q2.y + r[j+2].z*q2.z + r[j+2].w*q2.w;
      a3 += r[j+3].x*q3.x + r[j+3].y*q3.y + r[j+3].z*q3.z + r[j+3].w*q3.w;
    }
    float acc = (a0 + a1) + (a2 + a3);
    acc += __shfl_xor(acc, 1);          // combine halves
    // exp(10*tanh(x)-10) = exp(-20/(exp(2x)+1))
    e = (n != last) ? __expf(-20.f / (__expf(2.f*acc) + 1.f)) : 0.f;
    if (half == 0) out[b*NN + n] = e;   // unnormalized; kE scales in place
  }
  float s = (half == 0) ? e : 0.f;
  #pragma unroll
  for (int d = 1; d < 64; d <<= 1) s += __shfl_xor(s, d);
  if ((tid & 63) == 0) red[tid >> 6] = s;
  __syncthreads();
  if (tid == 0) psum[b*SPB + sp] = red[0] + red[1] + red[2] + red[3];
}

// ---------------- kE: in-place scale ----------------
__global__ __launch_bounds__(128) void kE(
    const float* __restrict__ psum, float* __restrict__ out) {
  const int b = blockIdx.y, sp = blockIdx.x, tid = threadIdx.x;
  float S = 0.f;
  #pragma unroll
  for (int s = 0; s < SPB; s++) S += psum[b*SPB + s];   // uniform s_loads
  const float inv = 1.f / S;
  const int n = sp*RPB + tid;
  if (tid < RPB) out[b*NN + n] *= inv;
}

// ---------------- host launch ----------------
extern "C" void kernel_launch(void* const* d_in, const int* in_sizes, int n_in,
                              void* d_out, int out_size, void* d_ws, size_t ws_size,
                              hipStream_t stream) {
  (void)in_sizes; (void)n_in; (void)out_size; (void)ws_size;
  const float* pe   = (const float*)d_in[0];
  const float* cls  = (const float*)d_in[1];
  const float* Wqg  = (const float*)d_in[2];
  const float* Wqf  = (const float*)d_in[3];
  const float* Wql  = (const float*)d_in[4];
  const float* Wk   = (const float*)d_in[5];
  const float* Wv   = (const float*)d_in[6];
  const float* lWk  = (const float*)d_in[7];
  const float* Wc   = (const float*)d_in[8];
  const float* bc   = (const float*)d_in[9];
  const int*   lp   = (const int*)d_in[10];
  float* out = (float*)d_out;
  float* ws  = (float*)d_ws;

  float* qk    = ws;                                  // 64*8*128
  float* Wpart = qk + BB*NHEAD*HH;                    // 64*16*8*128
  float* lpart = Wpart + (size_t)BB*SPB*NHEAD*HH;     // 64*16*8
  float* lq    = lpart + BB*SPB*NHEAD;                // 64*128
  float* psum  = lq + BB*HH;                          // 64*16

  k1qk<<<dim3(BB*NHEAD), dim3(64), 0, stream>>>(pe, cls, Wqg, Wqf, Wql, Wk, lp, qk);
  kB<<<dim3(SPB, BB), dim3(256), 0, stream>>>(pe, qk, lp, Wpart, lpart);
  kC<<<dim3(BB), dim3(256), 0, stream>>>(lpart, Wpart, Wv, Wc, bc, lWk, lq);
  kD<<<dim3(SPB, BB), dim3(256), 0, stream>>>(pe, lq, lp, out, psum);
  kE<<<dim3(SPB, BB), dim3(128), 0, stream>>>(psum, out);
}

// Round 10
// 86.046 us; speedup vs baseline: 1.1429x; 1.1429x over previous
//
#include <hip/hip_runtime.h>
#include <math.h>

#define BB 64
#define NN 2000
#define HH 128
#define NHEAD 8
#define SPB 16           // splits per batch for kB/kD/kE
#define RPB 125          // rows per block (SPB*RPB == NN)
#define SS 140           // stage row stride in floats (560 B, 16B-aligned, slot-spread)

// ---------------- k1qk: qk[b][h][:] , one block per (b,h) ----------------
__global__ __launch_bounds__(64) void k1qk(
    const float* __restrict__ pe, const float* __restrict__ cls,
    const float* __restrict__ Wqg, const float* __restrict__ Wqf,
    const float* __restrict__ Wql, const float* __restrict__ Wk,
    const int* __restrict__ lp, float* __restrict__ qk_out) {
  const int blk = blockIdx.x, b = blk >> 3, h = blk & 7;
  const int t = threadIdx.x;
  __shared__ float4 sc4[32], sl4[32];
  __shared__ float qs[16];
  const int last = lp[b];
  if (t < 32) sc4[t] = ((const float4*)(cls + b*HH))[t];
  else        sl4[t-32] = ((const float4*)(pe + ((long)b*NN + last)*HH))[t-32];
  __syncthreads();
  {
    const int dot = t >> 2, part = t & 3;
    const float4* wg = (const float4*)(Wqg + (h*16+dot)*HH) + part*8;
    const float4* wf = (const float4*)(Wqf + (h*16+dot)*HH) + part*8;
    const float4* wl = (const float4*)(Wql + (h*16+dot)*HH) + part*8;
    float a = 0.f;
    #pragma unroll
    for (int k = 0; k < 8; k++) {
      float4 g = wg[k], f = wf[k], l = wl[k];
      float4 c = sc4[part*8+k], s = sl4[part*8+k];
      a += g.x*c.x + g.y*c.y + g.z*c.z + g.w*c.w;
      a += (f.x+l.x)*s.x + (f.y+l.y)*s.y + (f.z+l.z)*s.z + (f.w+l.w)*s.w;
    }
    a += __shfl_xor(a, 1);
    a += __shfl_xor(a, 2);
    if (part == 0) qs[dot] = a;
  }
  __syncthreads();
  float v0 = 0.f, v1 = 0.f;
  #pragma unroll
  for (int d2 = 0; d2 < 16; d2++) {
    const float* wkr = Wk + (h*16+d2)*HH;
    float q = qs[d2];
    v0 += q * wkr[t];
    v1 += q * wkr[t+64];
  }
  qk_out[(b*NHEAD+h)*HH + t]      = v0 * 0.25f;   // fold 1/sqrt(head_dim)
  qk_out[(b*NHEAD+h)*HH + t + 64] = v1 * 0.25f;
}

// ---------------- kB: LDS-tiled scores + weighted sums (ONE global pass) ----------------
__global__ __launch_bounds__(256) void kB(
    const float* __restrict__ pe, const float* __restrict__ qk,
    const int* __restrict__ lp, float* __restrict__ Wpart,
    float* __restrict__ lpart) {
  const int b = blockIdx.y, sp = blockIdx.x, tid = threadIdx.x;
  __shared__ __align__(16) char arena[38016];
  float* stage = (float*)arena;                                  // [64][SS]
  float (*pl)[NHEAD]    = (float(*)[NHEAD])(arena + 35840);      // [64][8]
  float (*lred)[NHEAD]  = (float(*)[NHEAD])(arena + 37888);      // [4][8]
  float4 (*wred)[4][32] = (float4(*)[4][32])(arena);             // aliases stage (post-loop)

  const int last = lp[b];
  const int n0 = sp * RPB;
  const int w = tid >> 6, lane = tid & 63;
  const int st = w*2 + (lane >> 5);   // row stream 0..7
  const int j4 = lane & 31;
  const float4* peg = (const float4*)(pe + ((long)b*NN + n0)*HH);
  const float4* qk4 = (const float4*)(qk + (long)b*NHEAD*HH);    // uniform -> s_load

  float4 wa[NHEAD];
  float  la[NHEAD];
  #pragma unroll
  for (int h = 0; h < NHEAD; h++) { wa[h] = make_float4(0.f,0.f,0.f,0.f); la[h] = 0.f; }

  for (int t = 0; t < 2; ++t) {
    const int base = t*64;
    const int tsz = (RPB - base < 64) ? (RPB - base) : 64;   // 64 then 61
    // --- stage: coalesced global -> LDS (lane j4 reads consecutive float4 of row) ---
    #pragma unroll
    for (int i = 0; i < 8; ++i) {
      const int nl = st + i*8;
      if (nl < tsz)
        ((float4*)(stage + nl*SS))[j4] = peg[(base+nl)*32 + j4];
    }
    __syncthreads();
    // --- dots: 2 threads/row from LDS, qk via scalar path ---
    {
      const int row = tid >> 1, h2 = tid & 1;
      if (row < tsz) {
        const float4* sr = (const float4*)(stage + row*SS + h2*64);
        const float4* qh = qk4 + h2*16;
        float d[NHEAD];
        #pragma unroll
        for (int h = 0; h < NHEAD; h++) d[h] = 0.f;
        #pragma unroll
        for (int j = 0; j < 16; ++j) {
          const float4 v = sr[j];
          #pragma unroll
          for (int h = 0; h < NHEAD; h++) {
            const float4 q = qh[h*32 + j];
            d[h] += v.x*q.x + v.y*q.y + v.z*q.z + v.w*q.w;
          }
        }
        #pragma unroll
        for (int h = 0; h < NHEAD; h++) d[h] += __shfl_xor(d[h], 1);
        if (h2 == 0) {
          const bool live = (n0 + base + row != last);
          #pragma unroll
          for (int h = 0; h < NHEAD; h++) pl[row][h] = live ? __expf(d[h]) : 0.f;
        }
      }
    }
    __syncthreads();
    // --- weighted accumulate from LDS ---
    #pragma unroll
    for (int i = 0; i < 8; ++i) {
      const int nl = st + i*8;
      if (nl < tsz) {
        float4 v  = ((const float4*)(stage + nl*SS))[j4];
        float4 pa = *(const float4*)&pl[nl][0];
        float4 pb = *(const float4*)&pl[nl][4];
        wa[0].x += pa.x*v.x; wa[0].y += pa.x*v.y; wa[0].z += pa.x*v.z; wa[0].w += pa.x*v.w; la[0] += pa.x;
        wa[1].x += pa.y*v.x; wa[1].y += pa.y*v.y; wa[1].z += pa.y*v.z; wa[1].w += pa.y*v.w; la[1] += pa.y;
        wa[2].x += pa.z*v.x; wa[2].y += pa.z*v.y; wa[2].z += pa.z*v.z; wa[2].w += pa.z*v.w; la[2] += pa.z;
        wa[3].x += pa.w*v.x; wa[3].y += pa.w*v.y; wa[3].z += pa.w*v.z; wa[3].w += pa.w*v.w; la[3] += pa.w;
        wa[4].x += pb.x*v.x; wa[4].y += pb.x*v.y; wa[4].z += pb.x*v.z; wa[4].w += pb.x*v.w; la[4] += pb.x;
        wa[5].x += pb.y*v.x; wa[5].y += pb.y*v.y; wa[5].z += pb.y*v.z; wa[5].w += pb.y*v.w; la[5] += pb.y;
        wa[6].x += pb.z*v.x; wa[6].y += pb.z*v.y; wa[6].z += pb.z*v.z; wa[6].w += pb.z*v.w; la[6] += pb.z;
        wa[7].x += pb.w*v.x; wa[7].y += pb.w*v.y; wa[7].z += pb.w*v.z; wa[7].w += pb.w*v.w; la[7] += pb.w;
      }
    }
    __syncthreads();   // protect stage before next tile / wred alias
  }

  #pragma unroll
  for (int h = 0; h < NHEAD; h++) {     // merge the two half-wave streams
    wa[h].x += __shfl_xor(wa[h].x, 32);
    wa[h].y += __shfl_xor(wa[h].y, 32);
    wa[h].z += __shfl_xor(wa[h].z, 32);
    wa[h].w += __shfl_xor(wa[h].w, 32);
    la[h]   += __shfl_xor(la[h], 32);
  }
  if (lane < 32) {
    #pragma unroll
    for (int h = 0; h < NHEAD; h++) wred[h][w][lane] = wa[h];
  }
  if (lane == 0) {
    #pragma unroll
    for (int h = 0; h < NHEAD; h++) lred[w][h] = la[h];
  }
  __syncthreads();
  {
    const int h2 = tid >> 5, c = tid & 31;
    float4 s0 = wred[h2][0][c], s1 = wred[h2][1][c];
    float4 s2 = wred[h2][2][c], s3 = wred[h2][3][c];
    float4 s;
    s.x = s0.x + s1.x + s2.x + s3.x;
    s.y = s0.y + s1.y + s2.y + s3.y;
    s.z = s0.z + s1.z + s2.z + s3.z;
    s.w = s0.w + s1.w + s2.w + s3.w;
    ((float4*)(Wpart + ((long)(b*SPB + sp)*NHEAD + h2)*HH))[c] = s;
  }
  if (tid < NHEAD)
    lpart[(b*SPB + sp)*NHEAD + tid] =
        lred[0][tid] + lred[1][tid] + lred[2][tid] + lred[3][tid];
}

// ---------------- kC: combine splits + matvec chain -> lq ----------------
__global__ __launch_bounds__(256) void kC(
    const float* __restrict__ lpart, const float* __restrict__ Wpart,
    const float* __restrict__ Wv, const float* __restrict__ Wc,
    const float* __restrict__ bc, const float* __restrict__ lWk,
    float* __restrict__ lq) {
  const int b = blockIdx.x, tid = threadIdx.x;
  __shared__ float Wns[NHEAD*HH];
  __shared__ float lsm[NHEAD];
  __shared__ float tmp[2][HH];
  __shared__ float outf[HH], fq[HH];
  for (int e = tid; e < NHEAD*HH; e += 256) {
    float a = 0.f;
    #pragma unroll 4
    for (int s = 0; s < SPB; s++) a += Wpart[((long)(b*SPB+s)*NHEAD)*HH + e];
    Wns[e] = a;
  }
  if (tid < NHEAD) {
    float l = 0.f;
    #pragma unroll
    for (int s = 0; s < SPB; s++) l += lpart[(b*SPB+s)*NHEAD + tid];
    lsm[tid] = l;
  }
  __syncthreads();
  const int t = tid & 127, half = tid >> 7;
  {
    const int h = t >> 4;
    const float4* wv = (const float4*)(Wv + t*HH);
    const float4* wn = (const float4*)(Wns + h*HH);
    float a = 0.f;
    #pragma unroll 4
    for (int j = half*16; j < half*16 + 16; j++) {
      float4 v = wv[j], nn = wn[j];
      a += v.x*nn.x + v.y*nn.y + v.z*nn.z + v.w*nn.w;
    }
    tmp[half][t] = a;
    __syncthreads();
    if (half == 0) outf[t] = (tmp[0][t] + tmp[1][t]) / lsm[t>>4];
    __syncthreads();
  }
  {
    const float4* wc = (const float4*)(Wc + t*HH);
    const float4* of = (const float4*)outf;
    float a = 0.f;
    #pragma unroll 4
    for (int k = half*16; k < half*16 + 16; k++) {
      float4 v = wc[k], nn = of[k];
      a += v.x*nn.x + v.y*nn.y + v.z*nn.z + v.w*nn.w;
    }
    tmp[half][t] = a;
    __syncthreads();
    if (half == 0) fq[t] = tmp[0][t] + tmp[1][t] + bc[t];
    __syncthreads();
  }
  {
    float a = 0.f;
    #pragma unroll 4
    for (int i = half*64; i < half*64 + 64; i++)
      a += fq[i] * lWk[i*HH + t];
    tmp[half][t] = a;
    __syncthreads();
    if (half == 0)
      lq[b*HH + t] = (tmp[0][t] + tmp[1][t]) * 0.08838834764831845f;  // 1/sqrt(128)
  }
}

// ---------------- kD: LDS-tiled logits -> unnormalized e + psum ----------------
__global__ __launch_bounds__(256) void kD(
    const float* __restrict__ pe, const float* __restrict__ lq,
    const int* __restrict__ lp, float* __restrict__ out,
    float* __restrict__ psum) {
  const int b = blockIdx.y, sp = blockIdx.x, tid = threadIdx.x;
  __shared__ __align__(16) char arena[35856];
  float* stage = (float*)arena;                         // [64][SS]
  float* red   = (float*)(arena + 35840);               // [4]
  const int last = lp[b];
  const int n0 = sp * RPB;
  const int w = tid >> 6, lane = tid & 63;
  const int st = w*2 + (lane >> 5);
  const int j4 = lane & 31;
  const float4* peg = (const float4*)(pe + ((long)b*NN + n0)*HH);
  const float4* lq4 = (const float4*)(lq + (long)b*HH);  // uniform -> s_load

  float esum = 0.f;
  for (int t = 0; t < 2; ++t) {
    const int base = t*64;
    const int tsz = (RPB - base < 64) ? (RPB - base) : 64;
    #pragma unroll
    for (int i = 0; i < 8; ++i) {
      const int nl = st + i*8;
      if (nl < tsz)
        ((float4*)(stage + nl*SS))[j4] = peg[(base+nl)*32 + j4];
    }
    __syncthreads();
    {
      const int row = tid >> 1, h2 = tid & 1;
      if (row < tsz) {
        const float4* sr = (const float4*)(stage + row*SS + h2*64);
        const float4* qh = lq4 + h2*16;
        float a0 = 0.f, a1 = 0.f, a2 = 0.f, a3 = 0.f;
        #pragma unroll
        for (int j = 0; j < 16; j += 4) {
          float4 v0 = sr[j], v1 = sr[j+1], v2 = sr[j+2], v3 = sr[j+3];
          float4 q0 = qh[j], q1 = qh[j+1], q2 = qh[j+2], q3 = qh[j+3];
          a0 += v0.x*q0.x + v0.y*q0.y + v0.z*q0.z + v0.w*q0.w;
          a1 += v1.x*q1.x + v1.y*q1.y + v1.z*q1.z + v1.w*q1.w;
          a2 += v2.x*q2.x + v2.y*q2.y + v2.z*q2.z + v2.w*q2.w;
          a3 += v3.x*q3.x + v3.y*q3.y + v3.z*q3.z + v3.w*q3.w;
        }
        float acc = (a0 + a1) + (a2 + a3);
        acc += __shfl_xor(acc, 1);
        if (h2 == 0) {
          const int n = n0 + base + row;
          // exp(10*tanh(x)-10) = exp(-20/(exp(2x)+1))
          const float e = (n != last) ? __expf(-20.f / (__expf(2.f*acc) + 1.f)) : 0.f;
          out[b*NN + n] = e;    // unnormalized; kE scales in place
          esum += e;
        }
      }
    }
    __syncthreads();   // protect stage before next tile
  }
  float s = esum;
  #pragma unroll
  for (int d = 1; d < 64; d <<= 1) s += __shfl_xor(s, d);
  if (lane == 0) red[w] = s;
  __syncthreads();
  if (tid == 0) psum[b*SPB + sp] = red[0] + red[1] + red[2] + red[3];
}

// ---------------- kE: in-place scale ----------------
__global__ __launch_bounds__(128) void kE(
    const float* __restrict__ psum, float* __restrict__ out) {
  const int b = blockIdx.y, sp = blockIdx.x, tid = threadIdx.x;
  float S = 0.f;
  #pragma unroll
  for (int s = 0; s < SPB; s++) S += psum[b*SPB + s];   // uniform s_loads
  const float inv = 1.f / S;
  const int n = sp*RPB + tid;
  if (tid < RPB) out[b*NN + n] *= inv;
}

// ---------------- host launch ----------------
extern "C" void kernel_launch(void* const* d_in, const int* in_sizes, int n_in,
                              void* d_out, int out_size, void* d_ws, size_t ws_size,
                              hipStream_t stream) {
  (void)in_sizes; (void)n_in; (void)out_size; (void)ws_size;
  const float* pe   = (const float*)d_in[0];
  const float* cls  = (const float*)d_in[1];
  const float* Wqg  = (const float*)d_in[2];
  const float* Wqf  = (const float*)d_in[3];
  const float* Wql  = (const float*)d_in[4];
  const float* Wk   = (const float*)d_in[5];
  const float* Wv   = (const float*)d_in[6];
  const float* lWk  = (const float*)d_in[7];
  const float* Wc   = (const float*)d_in[8];
  const float* bc   = (const float*)d_in[9];
  const int*   lp   = (const int*)d_in[10];
  float* out = (float*)d_out;
  float* ws  = (float*)d_ws;

  float* qk    = ws;                                  // 64*8*128
  float* Wpart = qk + BB*NHEAD*HH;                    // 64*16*8*128
  float* lpart = Wpart + (size_t)BB*SPB*NHEAD*HH;     // 64*16*8
  float* lq    = lpart + BB*SPB*NHEAD;                // 64*128
  float* psum  = lq + BB*HH;                          // 64*16

  k1qk<<<dim3(BB*NHEAD), dim3(64), 0, stream>>>(pe, cls, Wqg, Wqf, Wql, Wk, lp, qk);
  kB<<<dim3(SPB, BB), dim3(256), 0, stream>>>(pe, qk, lp, Wpart, lpart);
  kC<<<dim3(BB), dim3(256), 0, stream>>>(lpart, Wpart, Wv, Wc, bc, lWk, lq);
  kD<<<dim3(SPB, BB), dim3(256), 0, stream>>>(pe, lq, lp, out, psum);
  kE<<<dim3(SPB, BB), dim3(128), 0, stream>>>(psum, out);
}